// Round 1
// baseline (89.683 us; speedup 1.0000x reference)
//
#include <hip/hip_runtime.h>
#include <math.h>

// Fuzzy LeNet-5, Yager p=1 == Lukasiewicz: T(a,b)=max(0,a+b-1).
// Fuzzy conv == max-plus conv: out = relu(max_{c,kh,kw}(x+w) - 1).
// maxpool2 folds into the conv via dilated 6x6 weights:
//   W'[uy][ux] = max_{dy,dx in {0,1}, uy-dy,ux-dx in [0,5)} w[uy-dy][ux-dx]
//
// R14: phase C rebalanced via u-split (336 -> 1008 tasks: tap-row u moves
// into the task index) so conv1 covers ~16 waves instead of 5.25 (worst-SIMD
// VALU was 2 waves x 756 insts). h-partials in BOTH conv phases now combine
// on the VALU pipe via a quad_perm DPP swap (h is lane bit 0), and only h==0
// lanes issue LDS atomics -- halves atomic lane traffic and kills the 2-way
// same-address RMW serialization. Window reduces are max3-tree shaped.
// Task bit order [(c,u) | (ocg,py,s) | h] keeps same-address atomic
// contributors in different waves (banks of active lanes provably distinct).
// Channel/u-partials still combined via LDS atomicMax on relu'd float bits
// (exact: relu>=0 floats order as uints; relu is monotone so
// relu(max-1)=max(relu(p-1)) for ANY partition of the max).

#define NT 1024
#define ROWS 34                 // padded image row stride
#define PLANE (32 * ROWS)       // 1088

__device__ __forceinline__ float dpp_pairmax(float v) {
    // quad_perm(1,0,3,2): swap adjacent lanes 2k<->2k+1. VALU pipe, no LDS.
    int p = __builtin_amdgcn_update_dpp(0, __float_as_int(v),
                                        0xB1, 0xF, 0xF, true);
    return fmaxf(v, __int_as_float(p));
}

__device__ __forceinline__ void dilate_row(const float* __restrict__ raw,
                                           int r, float* __restrict__ dst) {
    // dst[0..5] = max over kh in {r-1,r} cap [0,4], kw in {col-1,col} cap [0,4]
    const int rA = (r > 0) ? r - 1 : 0;
    const int rB = (r < 5) ? r : 4;
    float t0 = fmaxf(raw[rA * 5 + 0], raw[rB * 5 + 0]);
    float t1 = fmaxf(raw[rA * 5 + 1], raw[rB * 5 + 1]);
    float t2 = fmaxf(raw[rA * 5 + 2], raw[rB * 5 + 2]);
    float t3 = fmaxf(raw[rA * 5 + 3], raw[rB * 5 + 3]);
    float t4 = fmaxf(raw[rA * 5 + 4], raw[rB * 5 + 4]);
    float2* d = (float2*)dst;
    d[0] = make_float2(t0, fmaxf(t0, t1));
    d[1] = make_float2(fmaxf(t1, t2), fmaxf(t2, t3));
    d[2] = make_float2(fmaxf(t3, t4), t4);
}

__global__ __launch_bounds__(NT) void fused_lenet(
    const float* __restrict__ x,   // [B,3,32,32]
    const float* __restrict__ w1,  // [6,3,5,5]
    const float* __restrict__ w2,  // [16,6,5,5]
    const float* __restrict__ w3,  // [120,16,5,5]
    const float* __restrict__ wd,  // [120,84]
    const float* __restrict__ wf,  // [84,10]
    const float* __restrict__ bfv, // [10]
    float* __restrict__ out)       // [B,10]
{
    const int img = blockIdx.x;
    const int tid = threadIdx.x;

    __shared__ float s_in[3 * PLANE];          // 13056 B
    __shared__ float s_w1d[648];               // [oc][c][uy][6]
    __shared__ float s_w2d[3456];              // [oc][c][uy][6]
    __shared__ float s_wf[850];                // wf[840] + bf[10]
    __shared__ unsigned s_a1u[1176];           // conv1 out, relu'd float bits
    __shared__ unsigned s_a2u[400];            // conv2 out, relu'd float bits
    __shared__ float s_a3[120];
    __shared__ float s_a4[84];

    float4 w3p[13];   // filled after conv1 body, consumed in phase E

    // ---- Phase A: stage image + wf/bf + zero accums + dilate w1 AND w2
    //      (both dilations read global directly; latency hides under staging)
    {
        const float2* src = (const float2*)(x + img * 3072);
        for (int i = tid; i < 1536; i += NT) {
            const int c = i >> 9, rem = i & 511, r = rem >> 4, col2 = rem & 15;
            ((float2*)s_in)[c * (PLANE / 2) + r * (ROWS / 2) + col2] = src[i];
        }
        if (tid < 420) ((float2*)s_wf)[tid] = ((const float2*)wf)[tid];
        if (tid >= 428 && tid < 438) s_wf[840 + tid - 428] = bfv[tid - 428];
        for (int i = tid; i < 1176; i += NT) s_a1u[i] = 0u;
        if (tid < 400) s_a2u[tid] = 0u;
        if (tid >= 320 && tid < 428) {          // w1 dilation: 108 row-tasks
            const int e = tid - 320;
            const int occ = e / 6, r = e - occ * 6;   // occ = oc*3+c
            dilate_row(w1 + occ * 25, r, s_w1d + occ * 36 + r * 6);
        }
        if (tid >= 448) {                       // w2 dilation: 576 row-tasks
            const int e = tid - 448;
            const int occ = e / 6, r = e - occ * 6;   // occ = oc*6+c
            dilate_row(w2 + occ * 25, r, s_w2d + occ * 36 + r * 6);
        }
    }
    __syncthreads();

    // ---- Phase C: conv1 partials; 1008 tasks (c,u,ocg,py,s,h), 3 oc per
    //      task, ONE tap-row (uy = 3h+u) x 7-px strip. h pairs combine via
    //      DPP; (c,u) partials combine via LDS atomicMax from h==0 lanes.
    if (tid < 1008) {
        const int h = tid & 1;
        const int q = tid >> 1;                 // 0..503
        const int g = q / 56;                   // (c,u): 9 groups
        const int inner = q - g * 56;           // (ocg,py,s)
        const int c = g / 3;
        const int u = g - c * 3;
        const int ocg = inner / 28;
        const int it = inner - ocg * 28;
        const int py = it >> 1;                 // 0..13
        const int s = it & 1;
        const float* xbase =
            s_in + c * PLANE + (2 * py + 3 * h + u) * ROWS + 14 * s;
        float xv[18];
        #pragma unroll
        for (int iv = 0; iv < 9; ++iv)
            ((float2*)xv)[iv] = ((const float2*)xbase)[iv];
        #pragma unroll
        for (int o = 0; o < 3; ++o) {
            const float* wbase =
                s_w1d + ((ocg * 3 + o) * 3 + c) * 36 + (3 * h + u) * 6;
            float wv[6];
            #pragma unroll
            for (int iv = 0; iv < 3; ++iv)
                ((float2*)wv)[iv] = ((const float2*)wbase)[iv];
            float mrow[7];
            #pragma unroll
            for (int j = 0; j < 7; ++j) {
                const float t0 = xv[2 * j + 0] + wv[0];
                const float t1 = xv[2 * j + 1] + wv[1];
                const float t2 = xv[2 * j + 2] + wv[2];
                const float t3 = xv[2 * j + 3] + wv[3];
                const float t4 = xv[2 * j + 4] + wv[4];
                const float t5 = xv[2 * j + 5] + wv[5];
                const float m1 = fmaxf(fmaxf(t0, t1), t2);   // v_max3
                const float m2 = fmaxf(fmaxf(t3, t4), t5);   // v_max3
                mrow[j] = dpp_pairmax(fmaxf(m1, m2));
            }
            if (h == 0) {
                const int obase = (ocg * 3 + o) * 196 + py * 14 + 7 * s;
                #pragma unroll
                for (int j = 0; j < 7; ++j) {
                    const float rl = fmaxf(mrow[j] - 1.0f, 0.0f);
                    atomicMax(&s_a1u[obase + j], __float_as_uint(rl));
                }
            }
        }
    }
    // prefetch w3 into registers (in flight through conv2 + barriers, used E)
    if (tid < 960) {
        const int o = tid >> 3, q = tid & 7;
        const float4* wv = (const float4*)(w3 + o * 400);
        #pragma unroll
        for (int i = 0; i < 13; ++i) {
            int l = q + 8 * i; if (l > 99) l = 99;
            w3p[i] = wv[l];
        }
    }
    __syncthreads();

    // ---- Phase D: conv2 partials; 240 tasks (ocq,py,c,h), 4 oc per task,
    //      3 uy x 5-px row; h pairs combine via DPP, atomics from h==0 lanes
    if (tid < 240) {
        const int ocq = tid / 60;
        const int r = tid - ocq * 60;
        const int py = r / 12;
        const int r2 = r - py * 12;
        const int c = r2 >> 1;
        const int h = r2 & 1;                   // lane bit 0
        float acc[4][5];
        #pragma unroll
        for (int o = 0; o < 4; ++o)
            #pragma unroll
            for (int j = 0; j < 5; ++j) acc[o][j] = -1e30f;
        const float* a1f = (const float*)s_a1u;
        const float* xbase = a1f + c * 196 + (2 * py + 3 * h) * 14;
        #pragma unroll
        for (int u = 0; u < 3; ++u) {
            float xv[14];
            #pragma unroll
            for (int iv = 0; iv < 7; ++iv)
                ((float2*)xv)[iv] = ((const float2*)(xbase + u * 14))[iv];
            #pragma unroll
            for (int o = 0; o < 4; ++o) {
                const float* wbase =
                    s_w2d + ((ocq * 4 + o) * 6 + c) * 36 + h * 18 + u * 6;
                float wv[6];
                #pragma unroll
                for (int iv = 0; iv < 3; ++iv)
                    ((float2*)wv)[iv] = ((const float2*)wbase)[iv];
                #pragma unroll
                for (int j = 0; j < 5; ++j) {
                    const float t0 = xv[2 * j + 0] + wv[0];
                    const float t1 = xv[2 * j + 1] + wv[1];
                    const float t2 = xv[2 * j + 2] + wv[2];
                    const float t3 = xv[2 * j + 3] + wv[3];
                    const float t4 = xv[2 * j + 4] + wv[4];
                    const float t5 = xv[2 * j + 5] + wv[5];
                    const float m1 = fmaxf(fmaxf(t0, t1), t2);   // v_max3
                    const float m2 = fmaxf(fmaxf(t3, t4), t5);   // v_max3
                    acc[o][j] = fmaxf(acc[o][j], fmaxf(m1, m2)); // v_max3
                }
            }
        }
        #pragma unroll
        for (int o = 0; o < 4; ++o) {
            float comb[5];
            #pragma unroll
            for (int j = 0; j < 5; ++j) comb[j] = dpp_pairmax(acc[o][j]);
            if (h == 0) {
                const int obase = (ocq * 4 + o) * 25 + py * 5;
                #pragma unroll
                for (int j = 0; j < 5; ++j) {
                    const float rl = fmaxf(comb[j] - 1.0f, 0.0f);
                    atomicMax(&s_a2u[obase + j], __float_as_uint(rl));
                }
            }
        }
    }
    // prefetch wd for the dense phase (in flight during E)
    float wdp[15];
    if (tid < 672) {
        const int o = tid >> 3, q = tid & 7;
        #pragma unroll
        for (int i = 0; i < 15; ++i)
            wdp[i] = wd[(q * 15 + i) * 84 + o];
    }
    __syncthreads();

    // ---- Phase E: L3 [16,5,5]->[120]; 8 threads/output, prefetched w3
    if (tid < 960) {
        const int o = tid >> 3, q = tid & 7;
        const float4* av = (const float4*)(const float*)s_a2u;
        float m = -1e30f;
        #pragma unroll
        for (int i = 0; i < 13; ++i) {
            int l = q + 8 * i; if (l > 99) l = 99;
            const float4 a = av[l];
            const float4 w = w3p[i];
            m = fmaxf(m, fmaxf(fmaxf(a.x + w.x, a.y + w.y),
                               fmaxf(a.z + w.z, a.w + w.w)));
        }
        m = fmaxf(m, __shfl_xor(m, 1));
        m = fmaxf(m, __shfl_xor(m, 2));
        m = fmaxf(m, __shfl_xor(m, 4));
        if (q == 0) s_a3[o] = fmaxf(m - 1.0f, 0.0f);
    }
    __syncthreads();

    // ---- Phase F: dense [120]->[84] + tanh; 8 threads/output, prefetched wd
    if (tid < 672) {
        const int o = tid >> 3, q = tid & 7;
        float acc = 0.0f;
        #pragma unroll
        for (int i = 0; i < 15; ++i)
            acc = fmaf(s_a3[q * 15 + i], wdp[i], acc);
        acc += __shfl_xor(acc, 1);
        acc += __shfl_xor(acc, 2);
        acc += __shfl_xor(acc, 4);
        if (q == 0)
            s_a4[o] = 1.0f - 2.0f / (__expf(2.0f * acc) + 1.0f);  // tanh
    }
    __syncthreads();

    // ---- Phase G: fc [84]->[10] + bias + log_softmax, single wave, LDS-only
    if (tid < 64) {
        float acc = 0.0f;
        if (tid < 40) {
            const int o = tid >> 2, q = tid & 3;
            #pragma unroll 7
            for (int i = 0; i < 21; ++i) {
                const int k = q * 21 + i;
                acc = fmaf(s_a4[k], s_wf[k * 10 + o], acc);
            }
            acc += __shfl_xor(acc, 1);
            acc += __shfl_xor(acc, 2);
            acc += s_wf[840 + o];
        }
        const float lg = __shfl(acc, (tid < 10) ? tid * 4 : 0);
        if (tid < 16) {
            float v = (tid < 10) ? lg : -1e30f;
            #pragma unroll
            for (int d = 1; d < 16; d <<= 1)
                v = fmaxf(v, __shfl_xor(v, d));
            float e = (tid < 10) ? __expf(lg - v) : 0.0f;
            float ssum = e;
            #pragma unroll
            for (int d = 1; d < 16; d <<= 1)
                ssum += __shfl_xor(ssum, d);
            if (tid < 10)
                out[img * 10 + tid] = lg - v - __logf(ssum);
        }
    }
}

extern "C" void kernel_launch(void* const* d_in, const int* in_sizes, int n_in,
                              void* d_out, int out_size, void* d_ws, size_t ws_size,
                              hipStream_t stream) {
    const float* x   = (const float*)d_in[0];
    const float* w1  = (const float*)d_in[1];
    const float* w2  = (const float*)d_in[2];
    const float* w3  = (const float*)d_in[3];
    const float* wd  = (const float*)d_in[4];
    const float* wf  = (const float*)d_in[5];
    const float* bfv = (const float*)d_in[6];
    float* out = (float*)d_out;

    const int B = in_sizes[0] / (3 * 32 * 32);
    fused_lenet<<<dim3(B), dim3(NT), 0, stream>>>(
        x, w1, w2, w3, wd, wf, bfv, out);
}

// Round 2
// 74.319 us; speedup vs baseline: 1.2067x; 1.2067x over previous
//
#include <hip/hip_runtime.h>
#include <math.h>

// Fuzzy LeNet-5, Yager p=1 == Lukasiewicz: T(a,b)=max(0,a+b-1).
// Fuzzy conv == max-plus conv: out = relu(max_{c,kh,kw}(x+w) - 1).
// maxpool2 folds into the conv via dilated 6x6 weights:
//   W'[uy][ux] = max_{dy,dx in {0,1}, uy-dy,ux-dx in [0,5)} w[uy-dy][ux-dx]
//
// R15: FULL REVERT of R14's u-split/DPP restructure (regressed 73.6->89.7:
// work-preserving redistribution tripled same-address atomic contention and
// serialized the w3 prefetch behind conv1 on every wave). Back to the R13
// task layout, plus two strictly-local changes:
//  (1) all __syncthreads() -> lgkmcnt(0)-only raw barriers. All cross-thread
//      data here is LDS (lgkmcnt-tracked); __syncthreads' vmcnt(0) drain was
//      needlessly completing the thread-private w3p/wdp register prefetches
//      at each barrier. Raw barrier keeps them in flight until phase E/F use
//      (compiler inserts the dependency vmcnt waits automatically).
//  (2) 6-way window reduce shaped as max3 trees (dep chain 6 -> 2).
// Channel/h-partials combined via LDS atomicMax on relu'd float bits (exact:
// relu>=0 floats order as uints; relu(max-1)=max(relu(p-1))).

#define NT 1024
#define ROWS 34                 // padded image row stride
#define PLANE (32 * ROWS)       // 1088

// LDS-only workgroup barrier: waits LDS ops, leaves global loads in flight.
// Memory-clobber sandwich prevents hipcc from hoisting LDS reads across the
// barrier (rule: s_barrier intrinsic alone is not a scheduling fence).
__device__ __forceinline__ void bar_lds() {
    asm volatile("s_waitcnt lgkmcnt(0)" ::: "memory");
    __builtin_amdgcn_s_barrier();
    asm volatile("" ::: "memory");
}

__device__ __forceinline__ void dilate_row(const float* __restrict__ raw,
                                           int r, float* __restrict__ dst) {
    // dst[0..5] = max over kh in {r-1,r} cap [0,4], kw in {col-1,col} cap [0,4]
    const int rA = (r > 0) ? r - 1 : 0;
    const int rB = (r < 5) ? r : 4;
    float t0 = fmaxf(raw[rA * 5 + 0], raw[rB * 5 + 0]);
    float t1 = fmaxf(raw[rA * 5 + 1], raw[rB * 5 + 1]);
    float t2 = fmaxf(raw[rA * 5 + 2], raw[rB * 5 + 2]);
    float t3 = fmaxf(raw[rA * 5 + 3], raw[rB * 5 + 3]);
    float t4 = fmaxf(raw[rA * 5 + 4], raw[rB * 5 + 4]);
    float2* d = (float2*)dst;
    d[0] = make_float2(t0, fmaxf(t0, t1));
    d[1] = make_float2(fmaxf(t1, t2), fmaxf(t2, t3));
    d[2] = make_float2(fmaxf(t3, t4), t4);
}

__global__ __launch_bounds__(NT) void fused_lenet(
    const float* __restrict__ x,   // [B,3,32,32]
    const float* __restrict__ w1,  // [6,3,5,5]
    const float* __restrict__ w2,  // [16,6,5,5]
    const float* __restrict__ w3,  // [120,16,5,5]
    const float* __restrict__ wd,  // [120,84]
    const float* __restrict__ wf,  // [84,10]
    const float* __restrict__ bfv, // [10]
    float* __restrict__ out)       // [B,10]
{
    const int img = blockIdx.x;
    const int tid = threadIdx.x;

    __shared__ float s_in[3 * PLANE];          // 13056 B
    __shared__ float s_w1d[648];               // [oc][c][uy][6]
    __shared__ float s_w2d[3456];              // [oc][c][uy][6]
    __shared__ float s_wf[850];                // wf[840] + bf[10]
    __shared__ unsigned s_a1u[1176];           // conv1 out, relu'd float bits
    __shared__ unsigned s_a2u[400];            // conv2 out, relu'd float bits
    __shared__ float s_a3[120];
    __shared__ float s_a4[84];

    float4 w3p[13];   // filled after conv1 body, consumed in phase E

    // ---- Phase A: stage image + wf/bf + zero accums + dilate w1 AND w2
    //      (both dilations read global directly; latency hides under staging)
    {
        const float2* src = (const float2*)(x + img * 3072);
        for (int i = tid; i < 1536; i += NT) {
            const int c = i >> 9, rem = i & 511, r = rem >> 4, col2 = rem & 15;
            ((float2*)s_in)[c * (PLANE / 2) + r * (ROWS / 2) + col2] = src[i];
        }
        if (tid < 420) ((float2*)s_wf)[tid] = ((const float2*)wf)[tid];
        if (tid >= 428 && tid < 438) s_wf[840 + tid - 428] = bfv[tid - 428];
        for (int i = tid; i < 1176; i += NT) s_a1u[i] = 0u;
        if (tid < 400) s_a2u[tid] = 0u;
        if (tid >= 320 && tid < 428) {          // w1 dilation: 108 row-tasks
            const int e = tid - 320;
            const int occ = e / 6, r = e - occ * 6;   // occ = oc*3+c
            dilate_row(w1 + occ * 25, r, s_w1d + occ * 36 + r * 6);
        }
        if (tid >= 448) {                       // w2 dilation: 576 row-tasks
            const int e = tid - 448;
            const int occ = e / 6, r = e - occ * 6;   // occ = oc*6+c
            dilate_row(w2 + occ * 25, r, s_w2d + occ * 36 + r * 6);
        }
    }
    bar_lds();

    // ---- Phase C: conv1 partials; 336 tasks (c,ocg,py,s,h), 3 oc per task,
    //      3 uy x 7-px strip, x row loaded once per uy and reused across oc
    if (tid < 336) {
        const int c = tid / 112;
        const int r = tid - c * 112;
        const int ocg = r / 56;
        const int r2 = r - ocg * 56;
        const int py = r2 >> 2;
        const int s = (r2 >> 1) & 1;
        const int h = r2 & 1;
        float acc[3][7];
        #pragma unroll
        for (int o = 0; o < 3; ++o)
            #pragma unroll
            for (int j = 0; j < 7; ++j) acc[o][j] = -1e30f;
        const float* xbase = s_in + c * PLANE + (2 * py + 3 * h) * ROWS + 14 * s;
        #pragma unroll
        for (int u = 0; u < 3; ++u) {
            float xv[18];
            #pragma unroll
            for (int i2 = 0; i2 < 9; ++i2)
                ((float2*)xv)[i2] = ((const float2*)(xbase + u * ROWS))[i2];
            #pragma unroll
            for (int o = 0; o < 3; ++o) {
                const float* wbase =
                    s_w1d + ((ocg * 3 + o) * 3 + c) * 36 + h * 18 + u * 6;
                float wv[6];
                #pragma unroll
                for (int i2 = 0; i2 < 3; ++i2)
                    ((float2*)wv)[i2] = ((const float2*)wbase)[i2];
                #pragma unroll
                for (int j = 0; j < 7; ++j) {
                    const float t0 = xv[2 * j + 0] + wv[0];
                    const float t1 = xv[2 * j + 1] + wv[1];
                    const float t2 = xv[2 * j + 2] + wv[2];
                    const float t3 = xv[2 * j + 3] + wv[3];
                    const float t4 = xv[2 * j + 4] + wv[4];
                    const float t5 = xv[2 * j + 5] + wv[5];
                    const float m1 = fmaxf(fmaxf(t0, t1), t2);   // v_max3
                    const float m2 = fmaxf(fmaxf(t3, t4), t5);   // v_max3
                    acc[o][j] = fmaxf(acc[o][j], fmaxf(m1, m2)); // v_max3
                }
            }
        }
        #pragma unroll
        for (int o = 0; o < 3; ++o) {
            const int obase = (ocg * 3 + o) * 196 + py * 14 + 7 * s;
            #pragma unroll
            for (int j = 0; j < 7; ++j) {
                const float rl = fmaxf(acc[o][j] - 1.0f, 0.0f);
                atomicMax(&s_a1u[obase + j], __float_as_uint(rl));
            }
        }
    }
    // prefetch w3 into registers (in flight through conv2 + barriers, used E)
    if (tid < 960) {
        const int o = tid >> 3, q = tid & 7;
        const float4* wv = (const float4*)(w3 + o * 400);
        #pragma unroll
        for (int i = 0; i < 13; ++i) {
            int l = q + 8 * i; if (l > 99) l = 99;
            w3p[i] = wv[l];
        }
    }
    bar_lds();

    // ---- Phase D: conv2 partials; 240 tasks (ocq,py,c,h), 4 oc per task,
    //      3 uy x 5-px row, x row loaded once per uy and reused across oc
    if (tid < 240) {
        const int ocq = tid / 60;
        const int r = tid - ocq * 60;
        const int py = r / 12;
        const int r2 = r - py * 12;
        const int c = r2 >> 1;
        const int h = r2 & 1;
        float acc[4][5];
        #pragma unroll
        for (int o = 0; o < 4; ++o)
            #pragma unroll
            for (int j = 0; j < 5; ++j) acc[o][j] = -1e30f;
        const float* a1f = (const float*)s_a1u;
        const float* xbase = a1f + c * 196 + (2 * py + 3 * h) * 14;
        #pragma unroll
        for (int u = 0; u < 3; ++u) {
            float xv[14];
            #pragma unroll
            for (int i2 = 0; i2 < 7; ++i2)
                ((float2*)xv)[i2] = ((const float2*)(xbase + u * 14))[i2];
            #pragma unroll
            for (int o = 0; o < 4; ++o) {
                const float* wbase =
                    s_w2d + ((ocq * 4 + o) * 6 + c) * 36 + h * 18 + u * 6;
                float wv[6];
                #pragma unroll
                for (int i2 = 0; i2 < 3; ++i2)
                    ((float2*)wv)[i2] = ((const float2*)wbase)[i2];
                #pragma unroll
                for (int j = 0; j < 5; ++j) {
                    const float t0 = xv[2 * j + 0] + wv[0];
                    const float t1 = xv[2 * j + 1] + wv[1];
                    const float t2 = xv[2 * j + 2] + wv[2];
                    const float t3 = xv[2 * j + 3] + wv[3];
                    const float t4 = xv[2 * j + 4] + wv[4];
                    const float t5 = xv[2 * j + 5] + wv[5];
                    const float m1 = fmaxf(fmaxf(t0, t1), t2);   // v_max3
                    const float m2 = fmaxf(fmaxf(t3, t4), t5);   // v_max3
                    acc[o][j] = fmaxf(acc[o][j], fmaxf(m1, m2)); // v_max3
                }
            }
        }
        #pragma unroll
        for (int o = 0; o < 4; ++o) {
            const int obase = (ocq * 4 + o) * 25 + py * 5;
            #pragma unroll
            for (int j = 0; j < 5; ++j) {
                const float rl = fmaxf(acc[o][j] - 1.0f, 0.0f);
                atomicMax(&s_a2u[obase + j], __float_as_uint(rl));
            }
        }
    }
    // prefetch wd for the dense phase (in flight during E)
    float wdp[15];
    if (tid < 672) {
        const int o = tid >> 3, q = tid & 7;
        #pragma unroll
        for (int i = 0; i < 15; ++i)
            wdp[i] = wd[(q * 15 + i) * 84 + o];
    }
    bar_lds();

    // ---- Phase E: L3 [16,5,5]->[120]; 8 threads/output, prefetched w3
    if (tid < 960) {
        const int o = tid >> 3, q = tid & 7;
        const float4* av = (const float4*)(const float*)s_a2u;
        float m = -1e30f;
        #pragma unroll
        for (int i = 0; i < 13; ++i) {
            int l = q + 8 * i; if (l > 99) l = 99;
            const float4 a = av[l];
            const float4 w = w3p[i];
            m = fmaxf(m, fmaxf(fmaxf(a.x + w.x, a.y + w.y),
                               fmaxf(a.z + w.z, a.w + w.w)));
        }
        m = fmaxf(m, __shfl_xor(m, 1));
        m = fmaxf(m, __shfl_xor(m, 2));
        m = fmaxf(m, __shfl_xor(m, 4));
        if (q == 0) s_a3[o] = fmaxf(m - 1.0f, 0.0f);
    }
    bar_lds();

    // ---- Phase F: dense [120]->[84] + tanh; 8 threads/output, prefetched wd
    if (tid < 672) {
        const int o = tid >> 3, q = tid & 7;
        float acc = 0.0f;
        #pragma unroll
        for (int i = 0; i < 15; ++i)
            acc = fmaf(s_a3[q * 15 + i], wdp[i], acc);
        acc += __shfl_xor(acc, 1);
        acc += __shfl_xor(acc, 2);
        acc += __shfl_xor(acc, 4);
        if (q == 0)
            s_a4[o] = 1.0f - 2.0f / (__expf(2.0f * acc) + 1.0f);  // tanh
    }
    bar_lds();

    // ---- Phase G: fc [84]->[10] + bias + log_softmax, single wave, LDS-only
    if (tid < 64) {
        float acc = 0.0f;
        if (tid < 40) {
            const int o = tid >> 2, q = tid & 3;
            #pragma unroll 7
            for (int i = 0; i < 21; ++i) {
                const int k = q * 21 + i;
                acc = fmaf(s_a4[k], s_wf[k * 10 + o], acc);
            }
            acc += __shfl_xor(acc, 1);
            acc += __shfl_xor(acc, 2);
            acc += s_wf[840 + o];
        }
        const float lg = __shfl(acc, (tid < 10) ? tid * 4 : 0);
        if (tid < 16) {
            float v = (tid < 10) ? lg : -1e30f;
            #pragma unroll
            for (int d = 1; d < 16; d <<= 1)
                v = fmaxf(v, __shfl_xor(v, d));
            float e = (tid < 10) ? __expf(lg - v) : 0.0f;
            float ssum = e;
            #pragma unroll
            for (int d = 1; d < 16; d <<= 1)
                ssum += __shfl_xor(ssum, d);
            if (tid < 10)
                out[img * 10 + tid] = lg - v - __logf(ssum);
        }
    }
}

extern "C" void kernel_launch(void* const* d_in, const int* in_sizes, int n_in,
                              void* d_out, int out_size, void* d_ws, size_t ws_size,
                              hipStream_t stream) {
    const float* x   = (const float*)d_in[0];
    const float* w1  = (const float*)d_in[1];
    const float* w2  = (const float*)d_in[2];
    const float* w3  = (const float*)d_in[3];
    const float* wd  = (const float*)d_in[4];
    const float* wf  = (const float*)d_in[5];
    const float* bfv = (const float*)d_in[6];
    float* out = (float*)d_out;

    const int B = in_sizes[0] / (3 * 32 * 32);
    fused_lenet<<<dim3(B), dim3(NT), 0, stream>>>(
        x, w1, w2, w3, wd, wf, bfv, out);
}